// Round 3
// baseline (478.087 us; speedup 1.0000x reference)
//
#include <hip/hip_runtime.h>
#include <stdint.h>

#define T_DIM 8192
#define B_DIM 4096
#define NSEG 64                 // 64 segments x 128 rows (4 word-rows) each
#define NSTRIPE 16              // B_DIM / CTILE
#define CTILE 256               // columns per block
#define NBLOCKS (NSEG * NSTRIPE)
#define NEG_SLOPE 0.01f

typedef int   ivec4 __attribute__((ext_vector_type(4)));
typedef float fvec4 __attribute__((ext_vector_type(4)));

// Round-11 (= round-10 + compile fix): single kernel, counting-barrier scan.
// Phases: pack+publish (pure read stream) -> global counting barrier (1024
// blocks exactly resident at 4/CU x 256 CU) -> lookback as 16 INDEPENDENT
// pipelined loads/wave -> emit (pure write stream). Output stores cached
// (not nt): round-1 counters showed WRITE_SIZE = 2.08x output bytes with nt
// stores. Release/acquire ordering is carried by the barrier atomics
// themselves (__hip_atomic_fence does not exist in this ROCm).

__global__ __launch_bounds__(256, 4) void fused_scan(
        const int*   __restrict__ in,
        const float* __restrict__ delta,
        float*       __restrict__ out,
        unsigned long long* __restrict__ agg,   // [NSEG][B_DIM/4]
        unsigned int* __restrict__ done)        // counting barrier
{
    __shared__ int4 cnts[4][64];   // per-wordrow popcounts
    __shared__ int4 part[4][64];   // per-wave lookback partials

    const int stripe  = blockIdx.x;
    const int seg     = blockIdx.y;
    const int c4      = threadIdx.x & 63;      // column-quad lane
    const int rc      = threadIdx.x >> 6;      // word-row within segment, 0..3
    const int col0    = stripe * CTILE + c4 * 4;
    const int wordrow = seg * 4 + rc;          // global word row 0..255
    const int row0    = wordrow * 32;
    const int cq      = col0 >> 2;             // column-quad index, 0..1023

    // ---- pack: stream 32 rows x 4 cols (nt loads) into 4 bit-words ----
    const ivec4* __restrict__ inv = (const ivec4*)in;
    uint32_t b0 = 0, b1 = 0, b2 = 0, b3 = 0;
#pragma unroll
    for (int r = 0; r < 32; ++r) {
        ivec4 v = __builtin_nontemporal_load(&inv[((size_t)(row0 + r) * B_DIM + col0) >> 2]);
        b0 |= ((uint32_t)v.x & 1u) << r;
        b1 |= ((uint32_t)v.y & 1u) << r;
        b2 |= ((uint32_t)v.z & 1u) << r;
        b3 |= ((uint32_t)v.w & 1u) << r;
    }
    cnts[rc][c4] = make_int4(__popc(b0), __popc(b1), __popc(b2), __popc(b3));
    __syncthreads();

    // ---- publish segment aggregate (wave 0), then signal the barrier ----
    if (rc == 0) {
        int4 s = cnts[0][c4];
#pragma unroll
        for (int i = 1; i < 4; ++i) {
            int4 v = cnts[i][c4];
            s.x += v.x; s.y += v.y; s.z += v.z; s.w += v.w;
        }
        unsigned long long val =
              (unsigned long long)(unsigned)s.x
            | ((unsigned long long)(unsigned)s.y << 16)
            | ((unsigned long long)(unsigned)s.z << 32)
            | ((unsigned long long)(unsigned)s.w << 48);
        __hip_atomic_store(&agg[(size_t)seg * (B_DIM / 4) + cq], val,
                           __ATOMIC_RELAXED, __HIP_MEMORY_SCOPE_AGENT);
        // Release ordering on the signal orders the agg store before it.
        if (c4 == 0)
            __hip_atomic_fetch_add(done, 1u, __ATOMIC_RELEASE,
                                   __HIP_MEMORY_SCOPE_AGENT);
    }

    // ---- counting barrier: wait until all 1024 blocks have published ----
    if (seg > 0) {
        if (threadIdx.x == 0) {
            // Acquire ordering on the final (successful) load orders the
            // subsequent agg reads after all publishers' release-adds.
            while (__hip_atomic_load(done, __ATOMIC_ACQUIRE,
                                     __HIP_MEMORY_SCOPE_AGENT) < NBLOCKS)
                __builtin_amdgcn_s_sleep(2);
        }
        __syncthreads();
    }

    // ---- lookback: 16 independent (non-polling) loads per wave ----
    int c0 = 0, c1 = 0, c2 = 0, c3 = 0;
    for (int s = rc; s < seg; s += 4) {
        unsigned long long v = __hip_atomic_load(&agg[(size_t)s * (B_DIM / 4) + cq],
                                                 __ATOMIC_RELAXED, __HIP_MEMORY_SCOPE_AGENT);
        c0 += (int)( v        & 0xFFFF);
        c1 += (int)((v >> 16) & 0xFFFF);
        c2 += (int)((v >> 32) & 0xFFFF);
        c3 += (int)((v >> 48) & 0xFFFF);
    }
    part[rc][c4] = make_int4(c0, c1, c2, c3);
    __syncthreads();

    // ---- combine: global exclusive base + preceding word-rows in segment ----
    c0 = 0; c1 = 0; c2 = 0; c3 = 0;
#pragma unroll
    for (int i = 0; i < 4; ++i) {
        int4 v = part[i][c4];
        c0 += v.x; c1 += v.y; c2 += v.z; c3 += v.w;
    }
    for (int i = 0; i < rc; ++i) {   // rc is wave-uniform
        int4 v = cnts[i][c4];
        c0 += v.x; c1 += v.y; c2 += v.z; c3 += v.w;
    }

    const float d0 = delta[0];
    const float dd = delta[1] - d0;

    // ---- emit: leaky_relu((t+1)*d0 + ones*dd) straight from register bits ----
    // Plain (cached) stores: nt stores showed 2.08x HBM write amplification.
    fvec4* __restrict__ outv = (fvec4*)out;
#pragma unroll
    for (int r = 0; r < 32; ++r) {
        const int t = row0 + r;
        const float tp = (float)(t + 1) * d0;
        c0 += (int)((b0 >> r) & 1u);
        c1 += (int)((b1 >> r) & 1u);
        c2 += (int)((b2 >> r) & 1u);
        c3 += (int)((b3 >> r) & 1u);
        fvec4 o;
        float ox = fmaf((float)c0, dd, tp);
        float oy = fmaf((float)c1, dd, tp);
        float oz = fmaf((float)c2, dd, tp);
        float ow = fmaf((float)c3, dd, tp);
        o.x = (ox >= 0.0f) ? ox : NEG_SLOPE * ox;
        o.y = (oy >= 0.0f) ? oy : NEG_SLOPE * oy;
        o.z = (oz >= 0.0f) ? oz : NEG_SLOPE * oz;
        o.w = (ow >= 0.0f) ? ow : NEG_SLOPE * ow;
        outv[((size_t)t * B_DIM + col0) >> 2] = o;
    }
}

extern "C" void kernel_launch(void* const* d_in, const int* in_sizes, int n_in,
                              void* d_out, int out_size, void* d_ws, size_t ws_size,
                              hipStream_t stream) {
    const int*   in    = (const int*)d_in[0];
    const float* delta = (const float*)d_in[1];
    float*       out   = (float*)d_out;

    // ws layout: [done counter: 64 B][agg: NSEG * (B_DIM/4) * 8 B = 512 KiB]
    unsigned int* done = (unsigned int*)d_ws;
    unsigned long long* agg = (unsigned long long*)((char*)d_ws + 64);

    // Only the barrier counter needs zeroing (agg is fully written before any
    // read, guaranteed by the barrier). 64 B memset is near-free.
    (void)hipMemsetAsync(d_ws, 0, 64, stream);

    hipLaunchKernelGGL(fused_scan, dim3(NSTRIPE, NSEG), dim3(256), 0, stream,
                       in, delta, out, agg, done);
}

// Round 4
// 293.639 us; speedup vs baseline: 1.6281x; 1.6281x over previous
//
#include <hip/hip_runtime.h>
#include <stdint.h>

#define T_DIM 8192
#define B_DIM 4096
#define NSEG 64                 // 64 segments x 128 rows (4 word-rows) each
#define NSTRIPE 16              // B_DIM / CTILE
#define CTILE 256               // columns per block
#define NEG_SLOPE 0.01f

typedef int   ivec4 __attribute__((ext_vector_type(4)));
typedef float fvec4 __attribute__((ext_vector_type(4)));

// Round-12: round-1 decoupled-lookback structure (ticket-ordered segs,
// per-(seg,stripe) aggregate words, NO global counter -- round-3's single
// contended barrier line serialized the whole device at 1.4 TB/s), with the
// one defect fixed: the lookback is now BATCHED. All <=16 predecessor
// aggregates are issued as independent plain loads in one unrolled pass
// (one vmcnt wait instead of 16 serial round-trips); only the not-yet-ready
// entries are re-polled via agent-scope atomic loads (L1-bypassing).
// Readiness is carried by the +1-encoded value itself -> no fences.
// Deadlock-free for ANY residency: block tick t only waits on ticks < t
// (induction: lowest unfinished tick always progresses).

__global__ __launch_bounds__(256, 4) void fused_scan(
        const int*   __restrict__ in,
        const float* __restrict__ delta,
        float*       __restrict__ out,
        unsigned long long* __restrict__ agg,   // [NSEG][B_DIM/4], +1-encoded
        int*         __restrict__ ticket)
{
    __shared__ int  s_tick;
    __shared__ int4 cnts[4][64];   // per-wordrow popcounts
    __shared__ int4 part[4][64];   // per-wave lookback partials

    if (threadIdx.x == 0) s_tick = atomicAdd(ticket, 1);
    __syncthreads();
    const int tick   = s_tick;
    const int stripe = tick & (NSTRIPE - 1);
    const int seg    = tick >> 4;              // dispatch-order segment id

    const int c4      = threadIdx.x & 63;      // column-quad lane
    const int rc      = threadIdx.x >> 6;      // word-row within segment, 0..3
    const int col0    = stripe * CTILE + c4 * 4;
    const int wordrow = seg * 4 + rc;          // global word row 0..255
    const int row0    = wordrow * 32;
    const int cq      = col0 >> 2;             // column-quad index, 0..1023

    // ---- pack: stream 32 rows x 4 cols (nt loads) into 4 bit-words ----
    const ivec4* __restrict__ inv = (const ivec4*)in;
    uint32_t b0 = 0, b1 = 0, b2 = 0, b3 = 0;
#pragma unroll
    for (int r = 0; r < 32; ++r) {
        ivec4 v = __builtin_nontemporal_load(&inv[((size_t)(row0 + r) * B_DIM + col0) >> 2]);
        b0 |= ((uint32_t)v.x & 1u) << r;
        b1 |= ((uint32_t)v.y & 1u) << r;
        b2 |= ((uint32_t)v.z & 1u) << r;
        b3 |= ((uint32_t)v.w & 1u) << r;
    }
    cnts[rc][c4] = make_int4(__popc(b0), __popc(b1), __popc(b2), __popc(b3));
    __syncthreads();

    // ---- publish this segment's per-column aggregate ASAP (wave 0) ----
    if (rc == 0) {
        int4 s = cnts[0][c4];
#pragma unroll
        for (int i = 1; i < 4; ++i) {
            int4 v = cnts[i][c4];
            s.x += v.x; s.y += v.y; s.z += v.z; s.w += v.w;
        }
        unsigned long long val =
              (unsigned long long)(unsigned)(s.x + 1)
            | ((unsigned long long)(unsigned)(s.y + 1) << 16)
            | ((unsigned long long)(unsigned)(s.z + 1) << 32)
            | ((unsigned long long)(unsigned)(s.w + 1) << 48);
        __hip_atomic_store(&agg[(size_t)seg * (B_DIM / 4) + cq], val,
                           __ATOMIC_RELAXED, __HIP_MEMORY_SCOPE_AGENT);
    }

    // ---- batched lookback: wave rc owns s = rc, rc+4, ... (<=16 entries) --
    // First pass: plain loads, fully unrolled -> compiler pipelines all of
    // them behind ONE wait. L1 is invalidated at dispatch, so a first-touch
    // read is L2-fresh; a pre-publish read returns the memset 0 -> miss mask.
    int c0 = 0, c1 = 0, c2 = 0, c3 = 0;
    unsigned miss = 0;
#pragma unroll
    for (int i = 0; i < 16; ++i) {
        const int s = rc + 4 * i;
        if (s < seg) {
            unsigned long long v = agg[(size_t)s * (B_DIM / 4) + cq];
            if ((v & 0xFFFFull) == 0ull) {
                miss |= (1u << i);
            } else {
                c0 += (int)( v        & 0xFFFF) - 1;
                c1 += (int)((v >> 16) & 0xFFFF) - 1;
                c2 += (int)((v >> 32) & 0xFFFF) - 1;
                c3 += (int)((v >> 48) & 0xFFFF) - 1;
            }
        }
    }
    // Straggler re-poll: atomic (L1-bypassing) loads, only for missing bits.
    while (miss) {
        __builtin_amdgcn_s_sleep(4);
#pragma unroll
        for (int i = 0; i < 16; ++i) {
            if (miss & (1u << i)) {
                const int s = rc + 4 * i;
                unsigned long long v = __hip_atomic_load(
                    &agg[(size_t)s * (B_DIM / 4) + cq],
                    __ATOMIC_RELAXED, __HIP_MEMORY_SCOPE_AGENT);
                if ((v & 0xFFFFull) != 0ull) {
                    miss &= ~(1u << i);
                    c0 += (int)( v        & 0xFFFF) - 1;
                    c1 += (int)((v >> 16) & 0xFFFF) - 1;
                    c2 += (int)((v >> 32) & 0xFFFF) - 1;
                    c3 += (int)((v >> 48) & 0xFFFF) - 1;
                }
            }
        }
    }
    part[rc][c4] = make_int4(c0, c1, c2, c3);
    __syncthreads();

    // ---- combine: global exclusive base + preceding word-rows in segment --
    c0 = 0; c1 = 0; c2 = 0; c3 = 0;
#pragma unroll
    for (int i = 0; i < 4; ++i) {
        int4 v = part[i][c4];
        c0 += v.x; c1 += v.y; c2 += v.z; c3 += v.w;
    }
    for (int i = 0; i < rc; ++i) {   // rc is wave-uniform
        int4 v = cnts[i][c4];
        c0 += v.x; c1 += v.y; c2 += v.z; c3 += v.w;
    }

    const float d0 = delta[0];
    const float dd = delta[1] - d0;

    // ---- emit: leaky_relu((t+1)*d0 + ones*dd) straight from register bits --
    fvec4* __restrict__ outv = (fvec4*)out;
#pragma unroll
    for (int r = 0; r < 32; ++r) {
        const int t = row0 + r;
        const float tp = (float)(t + 1) * d0;
        c0 += (int)((b0 >> r) & 1u);
        c1 += (int)((b1 >> r) & 1u);
        c2 += (int)((b2 >> r) & 1u);
        c3 += (int)((b3 >> r) & 1u);
        fvec4 o;
        float ox = fmaf((float)c0, dd, tp);
        float oy = fmaf((float)c1, dd, tp);
        float oz = fmaf((float)c2, dd, tp);
        float ow = fmaf((float)c3, dd, tp);
        o.x = (ox >= 0.0f) ? ox : NEG_SLOPE * ox;
        o.y = (oy >= 0.0f) ? oy : NEG_SLOPE * oy;
        o.z = (oz >= 0.0f) ? oz : NEG_SLOPE * oz;
        o.w = (ow >= 0.0f) ? ow : NEG_SLOPE * ow;
        __builtin_nontemporal_store(o, &outv[((size_t)t * B_DIM + col0) >> 2]);
    }
}

extern "C" void kernel_launch(void* const* d_in, const int* in_sizes, int n_in,
                              void* d_out, int out_size, void* d_ws, size_t ws_size,
                              hipStream_t stream) {
    const int*   in    = (const int*)d_in[0];
    const float* delta = (const float*)d_in[1];
    float*       out   = (float*)d_out;

    // ws layout: [agg: NSEG * (B_DIM/4) * 8 B = 512 KiB][ticket: 64 B]
    unsigned long long* agg = (unsigned long long*)d_ws;
    const size_t agg_bytes  = (size_t)NSEG * (B_DIM / 4) * sizeof(unsigned long long);
    int* ticket = (int*)((char*)d_ws + agg_bytes);

    // agg must be zeroed each iteration (0 == not-ready sentinel; ws is
    // harness-poisoned between replays). 512 KiB memset ~ 1 us.
    (void)hipMemsetAsync(d_ws, 0, agg_bytes + 64, stream);

    hipLaunchKernelGGL(fused_scan, dim3(1024), dim3(256), 0, stream,
                       in, delta, out, agg, ticket);
}

// Round 5
// 232.928 us; speedup vs baseline: 2.0525x; 1.2606x over previous
//
#include <hip/hip_runtime.h>
#include <stdint.h>

#define T_DIM 8192
#define B_DIM 4096
#define NSEG 64                 // 64 segments x 128 rows (4 word-rows) each
#define CTILE 256               // columns per block
#define NEG_SLOPE 0.01f

// Native clang vector types: __builtin_nontemporal_* requires these.
typedef int      ivec4 __attribute__((ext_vector_type(4)));
typedef float    fvec4 __attribute__((ext_vector_type(4)));
typedef unsigned uvec4 __attribute__((ext_vector_type(4)));

// Round-13: back to the proven two-kernel structure (224.3 us baseline;
// every fused/megakernel variant made the kernel portion ~2x worse:
// 115-183 us vs ~60-65 us for KA+KB, with VALUBusy <10% -- intra-kernel
// waiting loses to the ~5 us inter-kernel barrier). Changes vs round-0:
//   1. seg_prefix kernel precomputes the exclusive per-column prefix of
//      segTotal (1 MiB, L2-hot, ~2-3 us), so KB does ONE int4 base load
//      instead of a 63-iteration walk (~260 MB aggregate L2 traffic).
//   2. KA pack loop grouped as 4x(8 loads -> pack) with static-indexed
//      register array: ~8 nt loads in flight per thread (deeper MLP).
//   3. No memset (no sentinels; ordering comes from kernel boundaries).

// ---------------------------------------------------------------------------
// KA: stream input (nt loads), pack 32 rows x 4 cols into register bit-words,
// write bits, publish per-segment column totals. Block = 256 cols x 128 rows.
// ---------------------------------------------------------------------------
__global__ __launch_bounds__(256, 4) void ka_pack(const int* __restrict__ in,
                                                  uint32_t* __restrict__ bits,
                                                  int* __restrict__ segTotal) {
    const int c4 = threadIdx.x & 63;           // column-quad lane
    const int rc = threadIdx.x >> 6;           // word-row within segment, 0..3
    const int col0 = blockIdx.x * CTILE + c4 * 4;
    const int wordrow = blockIdx.y * 4 + rc;   // global word row 0..255
    const int row0 = wordrow * 32;

    const ivec4* __restrict__ inv = (const ivec4*)in;
    uint32_t b0 = 0, b1 = 0, b2 = 0, b3 = 0;
#pragma unroll
    for (int g = 0; g < 4; ++g) {
        ivec4 v0 = __builtin_nontemporal_load(&inv[((size_t)(row0 + g * 8 + 0) * B_DIM + col0) >> 2]);
        ivec4 v1 = __builtin_nontemporal_load(&inv[((size_t)(row0 + g * 8 + 1) * B_DIM + col0) >> 2]);
        ivec4 v2 = __builtin_nontemporal_load(&inv[((size_t)(row0 + g * 8 + 2) * B_DIM + col0) >> 2]);
        ivec4 v3 = __builtin_nontemporal_load(&inv[((size_t)(row0 + g * 8 + 3) * B_DIM + col0) >> 2]);
        ivec4 v4 = __builtin_nontemporal_load(&inv[((size_t)(row0 + g * 8 + 4) * B_DIM + col0) >> 2]);
        ivec4 v5 = __builtin_nontemporal_load(&inv[((size_t)(row0 + g * 8 + 5) * B_DIM + col0) >> 2]);
        ivec4 v6 = __builtin_nontemporal_load(&inv[((size_t)(row0 + g * 8 + 6) * B_DIM + col0) >> 2]);
        ivec4 v7 = __builtin_nontemporal_load(&inv[((size_t)(row0 + g * 8 + 7) * B_DIM + col0) >> 2]);
        const int r = g * 8;
        b0 |= ((uint32_t)v0.x & 1u) << (r + 0); b1 |= ((uint32_t)v0.y & 1u) << (r + 0);
        b2 |= ((uint32_t)v0.z & 1u) << (r + 0); b3 |= ((uint32_t)v0.w & 1u) << (r + 0);
        b0 |= ((uint32_t)v1.x & 1u) << (r + 1); b1 |= ((uint32_t)v1.y & 1u) << (r + 1);
        b2 |= ((uint32_t)v1.z & 1u) << (r + 1); b3 |= ((uint32_t)v1.w & 1u) << (r + 1);
        b0 |= ((uint32_t)v2.x & 1u) << (r + 2); b1 |= ((uint32_t)v2.y & 1u) << (r + 2);
        b2 |= ((uint32_t)v2.z & 1u) << (r + 2); b3 |= ((uint32_t)v2.w & 1u) << (r + 2);
        b0 |= ((uint32_t)v3.x & 1u) << (r + 3); b1 |= ((uint32_t)v3.y & 1u) << (r + 3);
        b2 |= ((uint32_t)v3.z & 1u) << (r + 3); b3 |= ((uint32_t)v3.w & 1u) << (r + 3);
        b0 |= ((uint32_t)v4.x & 1u) << (r + 4); b1 |= ((uint32_t)v4.y & 1u) << (r + 4);
        b2 |= ((uint32_t)v4.z & 1u) << (r + 4); b3 |= ((uint32_t)v4.w & 1u) << (r + 4);
        b0 |= ((uint32_t)v5.x & 1u) << (r + 5); b1 |= ((uint32_t)v5.y & 1u) << (r + 5);
        b2 |= ((uint32_t)v5.z & 1u) << (r + 5); b3 |= ((uint32_t)v5.w & 1u) << (r + 5);
        b0 |= ((uint32_t)v6.x & 1u) << (r + 6); b1 |= ((uint32_t)v6.y & 1u) << (r + 6);
        b2 |= ((uint32_t)v6.z & 1u) << (r + 6); b3 |= ((uint32_t)v6.w & 1u) << (r + 6);
        b0 |= ((uint32_t)v7.x & 1u) << (r + 7); b1 |= ((uint32_t)v7.y & 1u) << (r + 7);
        b2 |= ((uint32_t)v7.z & 1u) << (r + 7); b3 |= ((uint32_t)v7.w & 1u) << (r + 7);
    }

    ((uint4*)bits)[((size_t)wordrow * B_DIM + col0) >> 2] = make_uint4(b0, b1, b2, b3);

    __shared__ int4 cnts[4][64];
    cnts[rc][c4] = make_int4(__popc(b0), __popc(b1), __popc(b2), __popc(b3));
    __syncthreads();

    if (rc == 0) {  // wave 0: column totals for this segment (4 word-rows)
        int4 s = cnts[0][c4];
#pragma unroll
        for (int i = 1; i < 4; ++i) {
            int4 v = cnts[i][c4];
            s.x += v.x; s.y += v.y; s.z += v.z; s.w += v.w;
        }
        ((int4*)segTotal)[((size_t)blockIdx.y * B_DIM + col0) >> 2] = s;
    }
}

// ---------------------------------------------------------------------------
// KM: exclusive prefix of segTotal along seg, per column. 64 x 4096 ints
// (1 MiB in, 1 MiB out), L2-hot. Thread owns one column; the 64 loads are
// independent (sum dependency only), so they pipeline behind one wait.
// ---------------------------------------------------------------------------
__global__ __launch_bounds__(256, 4) void seg_prefix(const int* __restrict__ segTotal,
                                                     int* __restrict__ base) {
    const int c = blockIdx.x * 256 + threadIdx.x;   // 16 blocks x 256 = 4096
    int sum = 0;
#pragma unroll
    for (int s = 0; s < NSEG; ++s) {
        base[(size_t)s * B_DIM + c] = sum;           // exclusive
        sum += segTotal[(size_t)s * B_DIM + c];
    }
}

// ---------------------------------------------------------------------------
// KB: reload packed bits (nt) + ONE base int4, reconstruct exact prefix
// count, emit leaky_relu via nt stores.
// ---------------------------------------------------------------------------
__global__ __launch_bounds__(256, 4) void kb_emit(const uint32_t* __restrict__ bits,
                                                  const int* __restrict__ base,
                                                  const float* __restrict__ delta,
                                                  float* __restrict__ out) {
    const int c4 = threadIdx.x & 63;
    const int rc = threadIdx.x >> 6;
    const int col0 = blockIdx.x * CTILE + c4 * 4;
    const int seg = blockIdx.y;
    const int wordrow = seg * 4 + rc;
    const int row0 = wordrow * 32;

    uvec4 w = __builtin_nontemporal_load(
        &((const uvec4*)bits)[((size_t)wordrow * B_DIM + col0) >> 2]);

    __shared__ int4 cnts[4][64];
    cnts[rc][c4] = make_int4(__popc(w.x), __popc(w.y), __popc(w.z), __popc(w.w));

    // base from preceding segments: single precomputed exclusive-prefix load
    int4 bv = ((const int4*)base)[((size_t)seg * B_DIM + col0) >> 2];
    int c0 = bv.x, c1 = bv.y, c2 = bv.z, c3 = bv.w;
    __syncthreads();

    // + preceding word-rows within segment (rc is wave-uniform)
    for (int i = 0; i < rc; ++i) {
        int4 v = cnts[i][c4];
        c0 += v.x; c1 += v.y; c2 += v.z; c3 += v.w;
    }

    const float d0 = delta[0];
    const float dd = delta[1] - d0;

    fvec4* __restrict__ outv = (fvec4*)out;
#pragma unroll
    for (int r = 0; r < 32; ++r) {
        const int t = row0 + r;
        const float tp = (float)(t + 1) * d0;
        c0 += (int)((w.x >> r) & 1u);
        c1 += (int)((w.y >> r) & 1u);
        c2 += (int)((w.z >> r) & 1u);
        c3 += (int)((w.w >> r) & 1u);
        fvec4 o;
        float ox = fmaf((float)c0, dd, tp);
        float oy = fmaf((float)c1, dd, tp);
        float oz = fmaf((float)c2, dd, tp);
        float ow = fmaf((float)c3, dd, tp);
        o.x = (ox >= 0.0f) ? ox : NEG_SLOPE * ox;
        o.y = (oy >= 0.0f) ? oy : NEG_SLOPE * oy;
        o.z = (oz >= 0.0f) ? oz : NEG_SLOPE * oz;
        o.w = (ow >= 0.0f) ? ow : NEG_SLOPE * ow;
        __builtin_nontemporal_store(o, &outv[((size_t)t * B_DIM + col0) >> 2]);
    }
}

extern "C" void kernel_launch(void* const* d_in, const int* in_sizes, int n_in,
                              void* d_out, int out_size, void* d_ws, size_t ws_size,
                              hipStream_t stream) {
    const int*   in    = (const int*)d_in[0];
    const float* delta = (const float*)d_in[1];
    float*       out   = (float*)d_out;

    // ws layout: [bits 4 MiB][segTotal 1 MiB][base 1 MiB]
    uint32_t* bits     = (uint32_t*)d_ws;
    int*      segTotal = (int*)((char*)d_ws + (size_t)(T_DIM / 32) * B_DIM * 4);
    int*      base     = (int*)((char*)d_ws + (size_t)(T_DIM / 32) * B_DIM * 4
                                            + (size_t)NSEG * B_DIM * 4);

    dim3 grid(B_DIM / CTILE, NSEG);   // (16, 64) = 1024 blocks
    dim3 block(256);

    hipLaunchKernelGGL(ka_pack, grid, block, 0, stream, in, bits, segTotal);
    hipLaunchKernelGGL(seg_prefix, dim3(16), block, 0, stream, segTotal, base);
    hipLaunchKernelGGL(kb_emit, grid, block, 0, stream, bits, base, delta, out);
}

// Round 6
// 226.988 us; speedup vs baseline: 2.1062x; 1.0262x over previous
//
#include <hip/hip_runtime.h>
#include <stdint.h>

#define T_DIM 8192
#define B_DIM 4096
#define NSEG 64                 // 64 segments x 128 rows (4 word-rows) each
#define CTILE 256               // columns per block
#define NEG_SLOPE 0.01f

// Native clang vector types: __builtin_nontemporal_* requires these.
typedef int      ivec4 __attribute__((ext_vector_type(4)));
typedef float    fvec4 __attribute__((ext_vector_type(4)));
typedef unsigned uvec4 __attribute__((ext_vector_type(4)));

// Round-14: round-0 champion (224.3 us) with ONE change: KB's segTotal walk
// is split across the 4 waves (s = rc, rc+4, ...) and combined in LDS,
// removing the 4x intra-block redundancy (258 MB -> 65 MB aggregate L2
// reads) and cutting the serial add chain 4x. Everything else is the exact
// round-0 code. Rejected by measurement: seg_prefix 3rd kernel (+8.6 us),
// megakernel fusion (kernel portion 2x worse), store-flavor changes
// (WRITE_SIZE "amplification" is poison-fill L3 writeback, not ours).

// ---------------------------------------------------------------------------
// KA: stream input (nt loads), pack 32 rows x 4 cols into register bit-words,
// write bits, publish per-segment column totals. Block = 256 cols x 128 rows.
// ---------------------------------------------------------------------------
__global__ __launch_bounds__(256, 4) void ka_pack(const int* __restrict__ in,
                                                  uint32_t* __restrict__ bits,
                                                  int* __restrict__ segTotal) {
    const int c4 = threadIdx.x & 63;           // column-quad lane
    const int rc = threadIdx.x >> 6;           // word-row within segment, 0..3
    const int col0 = blockIdx.x * CTILE + c4 * 4;
    const int wordrow = blockIdx.y * 4 + rc;   // global word row 0..255
    const int row0 = wordrow * 32;

    const ivec4* __restrict__ inv = (const ivec4*)in;
    uint32_t b0 = 0, b1 = 0, b2 = 0, b3 = 0;
#pragma unroll
    for (int r = 0; r < 32; ++r) {
        ivec4 v = __builtin_nontemporal_load(&inv[((size_t)(row0 + r) * B_DIM + col0) >> 2]);
        b0 |= ((uint32_t)v.x & 1u) << r;
        b1 |= ((uint32_t)v.y & 1u) << r;
        b2 |= ((uint32_t)v.z & 1u) << r;
        b3 |= ((uint32_t)v.w & 1u) << r;
    }

    ((uint4*)bits)[((size_t)wordrow * B_DIM + col0) >> 2] = make_uint4(b0, b1, b2, b3);

    __shared__ int4 cnts[4][64];
    cnts[rc][c4] = make_int4(__popc(b0), __popc(b1), __popc(b2), __popc(b3));
    __syncthreads();

    if (rc == 0) {  // wave 0: column totals for this segment (4 word-rows)
        int4 s = cnts[0][c4];
#pragma unroll
        for (int i = 1; i < 4; ++i) {
            int4 v = cnts[i][c4];
            s.x += v.x; s.y += v.y; s.z += v.z; s.w += v.w;
        }
        ((int4*)segTotal)[((size_t)blockIdx.y * B_DIM + col0) >> 2] = s;
    }
}

// ---------------------------------------------------------------------------
// KB: reload packed bits (nt) + segment totals (wave-split walk, combined in
// LDS), reconstruct exact prefix count, emit leaky_relu via nt stores.
// ---------------------------------------------------------------------------
__global__ __launch_bounds__(256, 4) void kb_emit(const uint32_t* __restrict__ bits,
                                                  const int* __restrict__ segTotal,
                                                  const float* __restrict__ delta,
                                                  float* __restrict__ out) {
    const int c4 = threadIdx.x & 63;
    const int rc = threadIdx.x >> 6;
    const int col0 = blockIdx.x * CTILE + c4 * 4;
    const int seg = blockIdx.y;
    const int wordrow = seg * 4 + rc;
    const int row0 = wordrow * 32;

    uvec4 w = __builtin_nontemporal_load(
        &((const uvec4*)bits)[((size_t)wordrow * B_DIM + col0) >> 2]);

    __shared__ int4 cnts[4][64];
    __shared__ int4 part[4][64];
    cnts[rc][c4] = make_int4(__popc(w.x), __popc(w.y), __popc(w.z), __popc(w.w));

    // Wave-split lookback: wave rc sums segments s = rc, rc+4, ... < seg.
    // (Round-0 had every wave loading all <=63 entries: 4x redundant.)
    int c0 = 0, c1 = 0, c2 = 0, c3 = 0;
    for (int s = rc; s < seg; s += 4) {
        int4 v = ((const int4*)segTotal)[((size_t)s * B_DIM + col0) >> 2];
        c0 += v.x; c1 += v.y; c2 += v.z; c3 += v.w;
    }
    part[rc][c4] = make_int4(c0, c1, c2, c3);
    __syncthreads();

    // Combine the 4 wave-partials (global exclusive base) + preceding
    // word-rows within the segment (rc is wave-uniform).
    c0 = 0; c1 = 0; c2 = 0; c3 = 0;
#pragma unroll
    for (int i = 0; i < 4; ++i) {
        int4 v = part[i][c4];
        c0 += v.x; c1 += v.y; c2 += v.z; c3 += v.w;
    }
    for (int i = 0; i < rc; ++i) {
        int4 v = cnts[i][c4];
        c0 += v.x; c1 += v.y; c2 += v.z; c3 += v.w;
    }

    const float d0 = delta[0];
    const float dd = delta[1] - d0;

    fvec4* __restrict__ outv = (fvec4*)out;
#pragma unroll
    for (int r = 0; r < 32; ++r) {
        const int t = row0 + r;
        const float tp = (float)(t + 1) * d0;
        c0 += (int)((w.x >> r) & 1u);
        c1 += (int)((w.y >> r) & 1u);
        c2 += (int)((w.z >> r) & 1u);
        c3 += (int)((w.w >> r) & 1u);
        fvec4 o;
        float ox = fmaf((float)c0, dd, tp);
        float oy = fmaf((float)c1, dd, tp);
        float oz = fmaf((float)c2, dd, tp);
        float ow = fmaf((float)c3, dd, tp);
        o.x = (ox >= 0.0f) ? ox : NEG_SLOPE * ox;
        o.y = (oy >= 0.0f) ? oy : NEG_SLOPE * oy;
        o.z = (oz >= 0.0f) ? oz : NEG_SLOPE * oz;
        o.w = (ow >= 0.0f) ? ow : NEG_SLOPE * ow;
        __builtin_nontemporal_store(o, &outv[((size_t)t * B_DIM + col0) >> 2]);
    }
}

extern "C" void kernel_launch(void* const* d_in, const int* in_sizes, int n_in,
                              void* d_out, int out_size, void* d_ws, size_t ws_size,
                              hipStream_t stream) {
    const int*   in    = (const int*)d_in[0];
    const float* delta = (const float*)d_in[1];
    float*       out   = (float*)d_out;

    uint32_t* bits     = (uint32_t*)d_ws;                                    // 4 MiB
    int*      segTotal = (int*)((char*)d_ws + (size_t)(T_DIM / 32) * B_DIM * 4);

    dim3 grid(B_DIM / CTILE, NSEG);   // (16, 64) = 1024 blocks
    dim3 block(256);

    hipLaunchKernelGGL(ka_pack, grid, block, 0, stream, in, bits, segTotal);
    hipLaunchKernelGGL(kb_emit, grid, block, 0, stream, bits, segTotal, delta, out);
}